// Round 7
// baseline (536.796 us; speedup 1.0000x reference)
//
#include <hip/hip_runtime.h>
#include <hip/hip_fp16.h>
#include <math.h>

// ---------------------------------------------------------------------------
// GCN 3-layer forward on MI355X.
// Round 6 change: GEMM was LDS-latency bound (VALU 24%, occ 15.7%: 16 uniform
// ds_read b128 + lgkmcnt wait serialized before each 64-FMA group). New GEMM:
// NO LDS. W read directly with wave-uniform indices -> scalar s_load into
// SGPRs (v_fma takes 1 SGPR operand); 2 rows/thread so each W value feeds 2
// FMAs; A streamed float4 one chunk ahead. Occupancy now VGPR-bound (~3
// waves/SIMD) and FMA stream has no in-k-row memory dependency.
// ---------------------------------------------------------------------------

__global__ __launch_bounds__(256) void edge_pass_kernel(const int* __restrict__ ei,
    const float* __restrict__ ew, unsigned long long* __restrict__ packed, int E) {
  int e = blockIdx.x * 256 + threadIdx.x;
  if (e >= E) return;
  int d = ei[E + e];                       // dst row of edge_index
  unsigned wfix = (unsigned)__float2uint_rn(ew[e] * 16777216.0f);  // Q24
  unsigned long long inc = (1ULL << 32) | (unsigned long long)wfix;
  atomicAdd(&packed[d], inc);
}

__global__ __launch_bounds__(256) void dinv_kernel(const unsigned long long* __restrict__ packed,
    float* __restrict__ dinv, int n) {
  int i = blockIdx.x * 256 + threadIdx.x;
  if (i >= n) return;
  float deg = 1.0f + (float)(unsigned)(packed[i] & 0xffffffffULL) * (1.0f / 16777216.0f);
  dinv[i] = 1.0f / sqrtf(deg);             // deg >= 1 always (self-loop weight 1)
}

// ---- 3-kernel exclusive scan of counts (hi32 of packed) -> row_ptr ---------
__global__ __launch_bounds__(1024) void scanA(const unsigned long long* __restrict__ packed,
    int* __restrict__ row_ptr, int* __restrict__ partials, int n) {
  __shared__ int sd[1024];
  int t = threadIdx.x;
  int i = blockIdx.x * 1024 + t;
  int v = (i < n) ? (int)(packed[i] >> 32) : 0;
  sd[t] = v;
  __syncthreads();
  for (int off = 1; off < 1024; off <<= 1) {
    int u = (t >= off) ? sd[t - off] : 0;
    __syncthreads();
    sd[t] += u;
    __syncthreads();
  }
  int incl = sd[t];
  if (i < n) row_ptr[i] = incl - v;           // block-local exclusive
  if (t == 1023) partials[blockIdx.x] = incl; // block total
}

__global__ __launch_bounds__(128) void scanB(int* partials, int nb) {
  __shared__ int sd[128];
  int t = threadIdx.x;
  int v = (t < nb) ? partials[t] : 0;
  sd[t] = v;
  __syncthreads();
  for (int off = 1; off < 128; off <<= 1) {
    int u = (t >= off) ? sd[t - off] : 0;
    __syncthreads();
    sd[t] += u;
    __syncthreads();
  }
  int incl = sd[t];
  partials[t] = incl - v;                     // exclusive block offsets
  if (t == nb - 1) partials[255] = incl;      // grand total -> slot 255
}

__global__ __launch_bounds__(1024) void scanC(int* row_ptr, const int* __restrict__ partials, int n) {
  int i = blockIdx.x * 1024 + threadIdx.x;
  if (i < n) row_ptr[i] += partials[blockIdx.x];
  if (i == 0) row_ptr[n] = partials[255];
}

__global__ __launch_bounds__(256) void fill_kernel(const int* __restrict__ ei,
    const float* __restrict__ ew, const float* __restrict__ dinv,
    const int* __restrict__ row_ptr, int* __restrict__ fillc,
    int2* __restrict__ epair, int E) {
  int e = blockIdx.x * 256 + threadIdx.x;
  if (e >= E) return;
  int s = ei[e], d = ei[E + e];
  float nw = dinv[s] * ew[e] * dinv[d];
  int p = row_ptr[d] + atomicAdd(&fillc[d], 1);
  epair[p] = make_int2(s, __float_as_int(nw));
}

__device__ __forceinline__ unsigned pkh2(float a, float b) {
  __half2 h = __float22half2_rn(make_float2(a, b));
  return *reinterpret_cast<unsigned*>(&h);
}

// ---- fp32 GEMM, 2 rows/thread, scalar-path W: Ch = fp16(A[M,128]@W[128,N])
// 128-thread blocks cover 256 rows; blockIdx.y = 64-col slice.
// W[k*N+col0+c] has wave-uniform index -> s_load (SGPR), no LDS at all.
template <int NCOL>
__global__ __launch_bounds__(128) void gemm_rows_kernel(const float* __restrict__ A,
    const float* __restrict__ W, unsigned short* __restrict__ Ch, int M, int N) {
  const int col0 = blockIdx.y * NCOL;
  const int t = threadIdx.x;
  const int r0 = blockIdx.x * 256 + t;
  const int r1 = r0 + 128;
  const bool v0 = r0 < M, v1 = r1 < M;
  const float4 z4 = make_float4(0.f, 0.f, 0.f, 0.f);
  const float4* a0p = (const float4*)(A + (size_t)r0 * 128);
  const float4* a1p = (const float4*)(A + (size_t)r1 * 128);
  float acc0[NCOL] = {}, acc1[NCOL] = {};
  float4 c0 = v0 ? a0p[0] : z4;
  float4 c1 = v1 ? a1p[0] : z4;
#pragma unroll 1
  for (int k4 = 0; k4 < 32; ++k4) {
    int nx = (k4 < 31) ? k4 + 1 : 31;        // last iter: harmless hot reload
    float4 n0 = v0 ? a0p[nx] : z4;
    float4 n1 = v1 ? a1p[nx] : z4;
    float a0v[4] = {c0.x, c0.y, c0.z, c0.w};
    float a1v[4] = {c1.x, c1.y, c1.z, c1.w};
#pragma unroll
    for (int kk = 0; kk < 4; ++kk) {
      const float* wr = W + (size_t)(k4 * 4 + kk) * N + col0;  // uniform addr
      float a0 = a0v[kk], a1 = a1v[kk];
#pragma unroll
      for (int c = 0; c < NCOL; ++c) {
        float wv = wr[c];                    // wave-uniform -> scalar load
        acc0[c] = fmaf(a0, wv, acc0[c]);
        acc1[c] = fmaf(a1, wv, acc1[c]);
      }
    }
    c0 = n0; c1 = n1;
  }
  if (v0) {
    unsigned short* hrow = Ch + (size_t)r0 * N + col0;
#pragma unroll
    for (int c = 0; c < NCOL; c += 8) {
      uint4 pk;
      pk.x = pkh2(acc0[c], acc0[c + 1]);
      pk.y = pkh2(acc0[c + 2], acc0[c + 3]);
      pk.z = pkh2(acc0[c + 4], acc0[c + 5]);
      pk.w = pkh2(acc0[c + 6], acc0[c + 7]);
      *(uint4*)&hrow[c] = pk;
    }
  }
  if (v1) {
    unsigned short* hrow = Ch + (size_t)r1 * N + col0;
#pragma unroll
    for (int c = 0; c < NCOL; c += 8) {
      uint4 pk;
      pk.x = pkh2(acc1[c], acc1[c + 1]);
      pk.y = pkh2(acc1[c + 2], acc1[c + 3]);
      pk.z = pkh2(acc1[c + 4], acc1[c + 5]);
      pk.w = pkh2(acc1[c + 6], acc1[c + 7]);
      *(uint4*)&hrow[c] = pk;
    }
  }
}

// ---- aggregation: out[n] = sum_{e: dst=n} norm_e * xw[src_e] + dinv^2*xw[n] + b
// All xw reads fp16 (gather 8B/lane, x4 unrolled; self-row also fp16).
template <int F, bool RELU>
__global__ __launch_bounds__(256) void agg_kernel(const unsigned short* __restrict__ xwh,
    const int* __restrict__ row_ptr, const int2* __restrict__ epair,
    const float* __restrict__ dinv, const float* __restrict__ bias,
    float* __restrict__ out, int Nn) {
  constexpr int LPN = F / 4;                  // lanes per node (4 dims each)
  int t = blockIdx.x * 256 + threadIdx.x;
  int node = t / LPN;
  int lane = t % LPN;
  if (node >= Nn) return;
  const uint2* xh = (const uint2*)xwh;        // 4 halves per uint2
  int start = row_ptr[node];
  int end = row_ptr[node + 1];
  float a0x = 0.f, a0y = 0.f, a0z = 0.f, a0w = 0.f;   // chain 0
  float a1x = 0.f, a1y = 0.f, a1z = 0.f, a1w = 0.f;   // chain 1
  int p = start;
  for (; p + 4 <= end; p += 4) {
    int2 e0 = epair[p];
    int2 e1 = epair[p + 1];
    int2 e2 = epair[p + 2];
    int2 e3 = epair[p + 3];
    uint2 u0 = xh[(size_t)e0.x * LPN + lane];
    uint2 u1 = xh[(size_t)e1.x * LPN + lane];
    uint2 u2 = xh[(size_t)e2.x * LPN + lane];
    uint2 u3 = xh[(size_t)e3.x * LPN + lane];
    float n0 = __int_as_float(e0.y), n1 = __int_as_float(e1.y);
    float n2 = __int_as_float(e2.y), n3 = __int_as_float(e3.y);
    float2 f0a = __half22float2(*(__half2*)&u0.x), f0b = __half22float2(*(__half2*)&u0.y);
    float2 f1a = __half22float2(*(__half2*)&u1.x), f1b = __half22float2(*(__half2*)&u1.y);
    float2 f2a = __half22float2(*(__half2*)&u2.x), f2b = __half22float2(*(__half2*)&u2.y);
    float2 f3a = __half22float2(*(__half2*)&u3.x), f3b = __half22float2(*(__half2*)&u3.y);
    a0x = fmaf(n0, f0a.x, a0x); a0y = fmaf(n0, f0a.y, a0y);
    a0z = fmaf(n0, f0b.x, a0z); a0w = fmaf(n0, f0b.y, a0w);
    a1x = fmaf(n1, f1a.x, a1x); a1y = fmaf(n1, f1a.y, a1y);
    a1z = fmaf(n1, f1b.x, a1z); a1w = fmaf(n1, f1b.y, a1w);
    a0x = fmaf(n2, f2a.x, a0x); a0y = fmaf(n2, f2a.y, a0y);
    a0z = fmaf(n2, f2b.x, a0z); a0w = fmaf(n2, f2b.y, a0w);
    a1x = fmaf(n3, f3a.x, a1x); a1y = fmaf(n3, f3a.y, a1y);
    a1z = fmaf(n3, f3b.x, a1z); a1w = fmaf(n3, f3b.y, a1w);
  }
  for (; p < end; ++p) {
    int2 pr = epair[p];
    float nw = __int_as_float(pr.y);
    uint2 u = xh[(size_t)pr.x * LPN + lane];
    float2 fa = __half22float2(*(__half2*)&u.x), fb = __half22float2(*(__half2*)&u.y);
    a0x = fmaf(nw, fa.x, a0x); a0y = fmaf(nw, fa.y, a0y);
    a0z = fmaf(nw, fb.x, a0z); a0w = fmaf(nw, fb.y, a0w);
  }
  float di = dinv[node];
  float sw = di * di;
  uint2 su = xh[(size_t)node * LPN + lane];   // fp16 self row
  float2 sa = __half22float2(*(__half2*)&su.x), sb = __half22float2(*(__half2*)&su.y);
  a0x = fmaf(sw, sa.x, a0x); a0y = fmaf(sw, sa.y, a0y);
  a0z = fmaf(sw, sb.x, a0z); a0w = fmaf(sw, sb.y, a0w);
  float4 b = ((const float4*)bias)[lane];
  float ox = a0x + a1x + b.x;
  float oy = a0y + a1y + b.y;
  float oz = a0z + a1z + b.z;
  float ow = a0w + a1w + b.w;
  if (RELU) {
    ox = fmaxf(ox, 0.f); oy = fmaxf(oy, 0.f);
    oz = fmaxf(oz, 0.f); ow = fmaxf(ow, 0.f);
  }
  ((float4*)out)[(size_t)node * LPN + lane] = make_float4(ox, oy, oz, ow);
}

// ---------------------------------------------------------------------------
extern "C" void kernel_launch(void* const* d_in, const int* in_sizes, int n_in,
                              void* d_out, int out_size, void* d_ws, size_t ws_size,
                              hipStream_t stream) {
  const float* x  = (const float*)d_in[0];
  const int*   ei = (const int*)d_in[1];     // int32, [2,E] flat
  const float* ew = (const float*)d_in[2];
  const float* W1 = (const float*)d_in[3];
  const float* b1 = (const float*)d_in[4];
  const float* W2 = (const float*)d_in[5];
  const float* b2 = (const float*)d_in[6];
  const float* W3 = (const float*)d_in[7];
  const float* b3 = (const float*)d_in[8];

  const int N = in_sizes[0] / 128;           // 100000
  const int E = in_sizes[2];                 // 1600000

  // workspace carve (256B aligned)
  char* ws = (char*)d_ws;
  size_t off = 0;
  auto carve = [&](size_t bytes) -> void* {
    void* p = ws + off;
    off += (bytes + 255) & ~(size_t)255;
    return p;
  };
  unsigned long long* packed = (unsigned long long*)carve((size_t)N * 8);
  int*   fillc   = (int*)carve((size_t)N * 4);
  float* dinv    = (float*)carve((size_t)N * 4);
  int*   row_ptr = (int*)carve((size_t)(N + 1) * 4);
  int*   parts   = (int*)carve(256 * 4);
  int2*  epair   = (int2*)carve((size_t)E * 8);
  float* bufF    = (float*)carve((size_t)N * 128 * 4);                 // fp32 h
  unsigned short* bufH = (unsigned short*)carve((size_t)N * 128 * 2);  // fp16 xw
  (void)ws_size; (void)n_in; (void)out_size;

  const int nThreads = 256;
  int gN  = (N + nThreads - 1) / nThreads;
  int gE  = (E + nThreads - 1) / nThreads;
  int nb  = (N + 1023) / 1024;               // scan blocks (98)

  // --- graph preprocessing (shared across the 3 layers) ---
  hipMemsetAsync(packed, 0, (size_t)N * 8, stream);
  hipMemsetAsync(fillc, 0, (size_t)N * 4, stream);
  edge_pass_kernel<<<gE, nThreads, 0, stream>>>(ei, ew, packed, E);
  dinv_kernel<<<gN, nThreads, 0, stream>>>(packed, dinv, N);
  scanA<<<nb, 1024, 0, stream>>>(packed, row_ptr, parts, N);
  scanB<<<1, 128, 0, stream>>>(parts, nb);
  scanC<<<nb, 1024, 0, stream>>>(row_ptr, parts, N);
  fill_kernel<<<gE, nThreads, 0, stream>>>(ei, ew, dinv, row_ptr, fillc, epair, E);

  const int gRows = (N + 255) / 256;         // 391 blocks of 256 rows
  int gAgg128 = (N * 32 + nThreads - 1) / nThreads;
  int gAgg64  = (N * 16 + nThreads - 1) / nThreads;

  // --- layer 1: xw1 = fp16(x@W1) -> bufH; aggregate+bias+relu -> bufF ---
  gemm_rows_kernel<64><<<dim3(gRows, 2), 128, 0, stream>>>(x, W1, bufH, N, 128);
  agg_kernel<128, true><<<gAgg128, nThreads, 0, stream>>>(bufH, row_ptr, epair, dinv, b1, bufF, N);

  // --- layer 2 (bufF -> bufH -> bufF) ---
  gemm_rows_kernel<64><<<dim3(gRows, 2), 128, 0, stream>>>(bufF, W2, bufH, N, 128);
  agg_kernel<128, true><<<gAgg128, nThreads, 0, stream>>>(bufH, row_ptr, epair, dinv, b2, bufF, N);

  // --- layer 3 (64-wide, no relu) -> d_out ---
  gemm_rows_kernel<64><<<dim3(gRows, 1), 128, 0, stream>>>(bufF, W3, bufH, N, 64);
  agg_kernel<64, false><<<gAgg64, nThreads, 0, stream>>>(bufH, row_ptr, epair, dinv, b3, (float*)d_out, N);
}

// Round 8
// 405.101 us; speedup vs baseline: 1.3251x; 1.3251x over previous
//
#include <hip/hip_runtime.h>
#include <hip/hip_fp16.h>
#include <math.h>

// ---------------------------------------------------------------------------
// GCN 3-layer forward on MI355X.
// Round 7 change: all vector-fp32 GEMMs plateaued ~90us (VALU 24%; spills or
// LDS-latency). Switch GEMM to MATRIX CORES via 3-term split-bf16:
//   A@W ~= Ah@Wh + Ah@Wl + Al@Wh   (bf16 hi/lo, fp32 MFMA accumulate)
// mfma_f32_16x16x32_bf16; W staged per-block in LDS transposed+XOR-swizzled
// (hi/lo, 64KB @ N=128); A streamed from global with 1-step prefetch.
// Added error ~1e-4/layer, threshold 1.235e-3.
// ---------------------------------------------------------------------------

typedef __bf16 bf16x8 __attribute__((ext_vector_type(8)));
typedef float f32x4 __attribute__((ext_vector_type(4)));

union BF8 {
  unsigned short u[8];
  uint4 q;
  bf16x8 v;
};

__device__ __forceinline__ unsigned short rne_bf16(float f) {
  unsigned u = __float_as_uint(f);
  u += 0x7fff + ((u >> 16) & 1);
  return (unsigned short)(u >> 16);
}
__device__ __forceinline__ float bf16_to_f(unsigned short h) {
  return __uint_as_float((unsigned)h << 16);
}

__global__ __launch_bounds__(256) void edge_pass_kernel(const int* __restrict__ ei,
    const float* __restrict__ ew, unsigned long long* __restrict__ packed, int E) {
  int e = blockIdx.x * 256 + threadIdx.x;
  if (e >= E) return;
  int d = ei[E + e];                       // dst row of edge_index
  unsigned wfix = (unsigned)__float2uint_rn(ew[e] * 16777216.0f);  // Q24
  unsigned long long inc = (1ULL << 32) | (unsigned long long)wfix;
  atomicAdd(&packed[d], inc);
}

__global__ __launch_bounds__(256) void dinv_kernel(const unsigned long long* __restrict__ packed,
    float* __restrict__ dinv, int n) {
  int i = blockIdx.x * 256 + threadIdx.x;
  if (i >= n) return;
  float deg = 1.0f + (float)(unsigned)(packed[i] & 0xffffffffULL) * (1.0f / 16777216.0f);
  dinv[i] = 1.0f / sqrtf(deg);             // deg >= 1 always (self-loop weight 1)
}

// ---- 3-kernel exclusive scan of counts (hi32 of packed) -> row_ptr ---------
__global__ __launch_bounds__(1024) void scanA(const unsigned long long* __restrict__ packed,
    int* __restrict__ row_ptr, int* __restrict__ partials, int n) {
  __shared__ int sd[1024];
  int t = threadIdx.x;
  int i = blockIdx.x * 1024 + t;
  int v = (i < n) ? (int)(packed[i] >> 32) : 0;
  sd[t] = v;
  __syncthreads();
  for (int off = 1; off < 1024; off <<= 1) {
    int u = (t >= off) ? sd[t - off] : 0;
    __syncthreads();
    sd[t] += u;
    __syncthreads();
  }
  int incl = sd[t];
  if (i < n) row_ptr[i] = incl - v;           // block-local exclusive
  if (t == 1023) partials[blockIdx.x] = incl; // block total
}

__global__ __launch_bounds__(128) void scanB(int* partials, int nb) {
  __shared__ int sd[128];
  int t = threadIdx.x;
  int v = (t < nb) ? partials[t] : 0;
  sd[t] = v;
  __syncthreads();
  for (int off = 1; off < 128; off <<= 1) {
    int u = (t >= off) ? sd[t - off] : 0;
    __syncthreads();
    sd[t] += u;
    __syncthreads();
  }
  int incl = sd[t];
  partials[t] = incl - v;                     // exclusive block offsets
  if (t == nb - 1) partials[255] = incl;      // grand total -> slot 255
}

__global__ __launch_bounds__(1024) void scanC(int* row_ptr, const int* __restrict__ partials, int n) {
  int i = blockIdx.x * 1024 + threadIdx.x;
  if (i < n) row_ptr[i] += partials[blockIdx.x];
  if (i == 0) row_ptr[n] = partials[255];
}

__global__ __launch_bounds__(256) void fill_kernel(const int* __restrict__ ei,
    const float* __restrict__ ew, const float* __restrict__ dinv,
    const int* __restrict__ row_ptr, int* __restrict__ fillc,
    int2* __restrict__ epair, int E) {
  int e = blockIdx.x * 256 + threadIdx.x;
  if (e >= E) return;
  int s = ei[e], d = ei[E + e];
  float nw = dinv[s] * ew[e] * dinv[d];
  int p = row_ptr[d] + atomicAdd(&fillc[d], 1);
  epair[p] = make_int2(s, __float_as_int(nw));
}

// ---- MFMA split-bf16 GEMM: Ch[M,NCOL] = fp16(A[M,128] @ W[128,NCOL]) -------
// Block: 256 thr = 4 waves, 64 rows (16/wave) x NCOL cols. K=128 in 4 steps.
// LDS: WT[2][NCOL][128] bf16 (hi,lo), transposed W, k-index XOR-swizzled by
// (n&7)<<3 -> B-frag ds_read_b128 ~conflict-free. A from global, 1-step
// prefetch. Fragments (16x16x32): A/B lane l -> row/col=l&15, k=(l>>4)*8+j;
// C/D lane l reg j -> col=l&15, row=(l>>4)*4+j (HW-verified mapping).
template <int NCOL>
__global__ __launch_bounds__(256) void gemm_mfma_kernel(const float* __restrict__ A,
    const float* __restrict__ W, unsigned short* __restrict__ Ch, int M) {
  constexpr int NF = NCOL / 16;
  __shared__ __align__(16) unsigned short WT[2][NCOL][128];
  const int t = threadIdx.x;
  // --- stage W -> LDS as bf16 hi/lo, transposed + swizzled ---
  // thread covers (n, k-chunk): n = t % NCOL, kc = it*(256/NCOL) + t/NCOL
  constexpr int KC_PER_IT = 256 / NCOL;       // k-chunks advanced per iter
#pragma unroll
  for (int it = 0; it < 16 / KC_PER_IT; ++it) {
    int n = t % NCOL;
    int kc = it * KC_PER_IT + t / NCOL;
    int k0 = kc * 8;
    BF8 hh, ll;
#pragma unroll
    for (int j = 0; j < 8; ++j) {
      float w = W[(size_t)(k0 + j) * NCOL + n];
      unsigned short hb = rne_bf16(w);
      hh.u[j] = hb;
      ll.u[j] = rne_bf16(w - bf16_to_f(hb));
    }
    int kk = k0 ^ ((n & 7) << 3);
    *(uint4*)&WT[0][n][kk] = hh.q;
    *(uint4*)&WT[1][n][kk] = ll.q;
  }
  __syncthreads();

  const int wv = t >> 6;                      // wave 0..3
  const int l = t & 63;
  const int lr = l & 15;                      // A-row / B-col / C-col selector
  const int lg = l >> 4;                      // k-group
  const int arow_i = blockIdx.x * 64 + wv * 16 + lr;
  const bool rv = arow_i < M;
  const float* arow = A + (size_t)arow_i * 128;

  f32x4 acc[NF] = {};
  float4 p0 = make_float4(0.f, 0.f, 0.f, 0.f), p1 = p0;
  if (rv) {
    p0 = *(const float4*)&arow[lg * 8];
    p1 = *(const float4*)&arow[lg * 8 + 4];
  }
#pragma unroll 1
  for (int ks = 0; ks < 4; ++ks) {
    // prefetch next A chunk (last iter: hot reload of current)
    int nkb = ((ks < 3) ? (ks + 1) * 32 : ks * 32) + lg * 8;
    float4 q0 = make_float4(0.f, 0.f, 0.f, 0.f), q1 = q0;
    if (rv) {
      q0 = *(const float4*)&arow[nkb];
      q1 = *(const float4*)&arow[nkb + 4];
    }
    // convert current A chunk to bf16 hi/lo
    float av[8] = {p0.x, p0.y, p0.z, p0.w, p1.x, p1.y, p1.z, p1.w};
    BF8 ah, al;
#pragma unroll
    for (int j = 0; j < 8; ++j) {
      unsigned short hb = rne_bf16(av[j]);
      ah.u[j] = hb;
      al.u[j] = rne_bf16(av[j] - bf16_to_f(hb));
    }
    // B fragments from LDS
    int kidx = ks * 32 + lg * 8;
    BF8 bh[NF], bl[NF];
#pragma unroll
    for (int nf = 0; nf < NF; ++nf) {
      int n = nf * 16 + lr;
      int kk = kidx ^ ((n & 7) << 3);
      bh[nf].q = *(const uint4*)&WT[0][n][kk];
      bl[nf].q = *(const uint4*)&WT[1][n][kk];
    }
#pragma unroll
    for (int nf = 0; nf < NF; ++nf) {
      acc[nf] = __builtin_amdgcn_mfma_f32_16x16x32_bf16(ah.v, bh[nf].v, acc[nf], 0, 0, 0);
      acc[nf] = __builtin_amdgcn_mfma_f32_16x16x32_bf16(al.v, bh[nf].v, acc[nf], 0, 0, 0);
      acc[nf] = __builtin_amdgcn_mfma_f32_16x16x32_bf16(ah.v, bl[nf].v, acc[nf], 0, 0, 0);
    }
    p0 = q0; p1 = q1;
  }
  // --- epilogue: fp16 store; C row = base + lg*4 + j, col = nf*16 + lr ---
  const int orow0 = blockIdx.x * 64 + wv * 16 + lg * 4;
#pragma unroll
  for (int j = 0; j < 4; ++j) {
    int orow = orow0 + j;
    if (orow < M) {
      unsigned short* hr = Ch + (size_t)orow * NCOL;
#pragma unroll
      for (int nf = 0; nf < NF; ++nf)
        hr[nf * 16 + lr] = __half_as_ushort(__float2half(acc[nf][j]));
    }
  }
}

// ---- aggregation: out[n] = sum_{e: dst=n} norm_e * xw[src_e] + dinv^2*xw[n] + b
// All xw reads fp16 (gather 8B/lane, x4 unrolled; self-row also fp16).
template <int F, bool RELU>
__global__ __launch_bounds__(256) void agg_kernel(const unsigned short* __restrict__ xwh,
    const int* __restrict__ row_ptr, const int2* __restrict__ epair,
    const float* __restrict__ dinv, const float* __restrict__ bias,
    float* __restrict__ out, int Nn) {
  constexpr int LPN = F / 4;                  // lanes per node (4 dims each)
  int t = blockIdx.x * 256 + threadIdx.x;
  int node = t / LPN;
  int lane = t % LPN;
  if (node >= Nn) return;
  const uint2* xh = (const uint2*)xwh;        // 4 halves per uint2
  int start = row_ptr[node];
  int end = row_ptr[node + 1];
  float a0x = 0.f, a0y = 0.f, a0z = 0.f, a0w = 0.f;   // chain 0
  float a1x = 0.f, a1y = 0.f, a1z = 0.f, a1w = 0.f;   // chain 1
  int p = start;
  for (; p + 4 <= end; p += 4) {
    int2 e0 = epair[p];
    int2 e1 = epair[p + 1];
    int2 e2 = epair[p + 2];
    int2 e3 = epair[p + 3];
    uint2 u0 = xh[(size_t)e0.x * LPN + lane];
    uint2 u1 = xh[(size_t)e1.x * LPN + lane];
    uint2 u2 = xh[(size_t)e2.x * LPN + lane];
    uint2 u3 = xh[(size_t)e3.x * LPN + lane];
    float n0 = __int_as_float(e0.y), n1 = __int_as_float(e1.y);
    float n2 = __int_as_float(e2.y), n3 = __int_as_float(e3.y);
    float2 f0a = __half22float2(*(__half2*)&u0.x), f0b = __half22float2(*(__half2*)&u0.y);
    float2 f1a = __half22float2(*(__half2*)&u1.x), f1b = __half22float2(*(__half2*)&u1.y);
    float2 f2a = __half22float2(*(__half2*)&u2.x), f2b = __half22float2(*(__half2*)&u2.y);
    float2 f3a = __half22float2(*(__half2*)&u3.x), f3b = __half22float2(*(__half2*)&u3.y);
    a0x = fmaf(n0, f0a.x, a0x); a0y = fmaf(n0, f0a.y, a0y);
    a0z = fmaf(n0, f0b.x, a0z); a0w = fmaf(n0, f0b.y, a0w);
    a1x = fmaf(n1, f1a.x, a1x); a1y = fmaf(n1, f1a.y, a1y);
    a1z = fmaf(n1, f1b.x, a1z); a1w = fmaf(n1, f1b.y, a1w);
    a0x = fmaf(n2, f2a.x, a0x); a0y = fmaf(n2, f2a.y, a0y);
    a0z = fmaf(n2, f2b.x, a0z); a0w = fmaf(n2, f2b.y, a0w);
    a1x = fmaf(n3, f3a.x, a1x); a1y = fmaf(n3, f3a.y, a1y);
    a1z = fmaf(n3, f3b.x, a1z); a1w = fmaf(n3, f3b.y, a1w);
  }
  for (; p < end; ++p) {
    int2 pr = epair[p];
    float nw = __int_as_float(pr.y);
    uint2 u = xh[(size_t)pr.x * LPN + lane];
    float2 fa = __half22float2(*(__half2*)&u.x), fb = __half22float2(*(__half2*)&u.y);
    a0x = fmaf(nw, fa.x, a0x); a0y = fmaf(nw, fa.y, a0y);
    a0z = fmaf(nw, fb.x, a0z); a0w = fmaf(nw, fb.y, a0w);
  }
  float di = dinv[node];
  float sw = di * di;
  uint2 su = xh[(size_t)node * LPN + lane];   // fp16 self row
  float2 sa = __half22float2(*(__half2*)&su.x), sb = __half22float2(*(__half2*)&su.y);
  a0x = fmaf(sw, sa.x, a0x); a0y = fmaf(sw, sa.y, a0y);
  a0z = fmaf(sw, sb.x, a0z); a0w = fmaf(sw, sb.y, a0w);
  float4 b = ((const float4*)bias)[lane];
  float ox = a0x + a1x + b.x;
  float oy = a0y + a1y + b.y;
  float oz = a0z + a1z + b.z;
  float ow = a0w + a1w + b.w;
  if (RELU) {
    ox = fmaxf(ox, 0.f); oy = fmaxf(oy, 0.f);
    oz = fmaxf(oz, 0.f); ow = fmaxf(ow, 0.f);
  }
  ((float4*)out)[(size_t)node * LPN + lane] = make_float4(ox, oy, oz, ow);
}

// ---------------------------------------------------------------------------
extern "C" void kernel_launch(void* const* d_in, const int* in_sizes, int n_in,
                              void* d_out, int out_size, void* d_ws, size_t ws_size,
                              hipStream_t stream) {
  const float* x  = (const float*)d_in[0];
  const int*   ei = (const int*)d_in[1];     // int32, [2,E] flat
  const float* ew = (const float*)d_in[2];
  const float* W1 = (const float*)d_in[3];
  const float* b1 = (const float*)d_in[4];
  const float* W2 = (const float*)d_in[5];
  const float* b2 = (const float*)d_in[6];
  const float* W3 = (const float*)d_in[7];
  const float* b3 = (const float*)d_in[8];

  const int N = in_sizes[0] / 128;           // 100000
  const int E = in_sizes[2];                 // 1600000

  // workspace carve (256B aligned)
  char* ws = (char*)d_ws;
  size_t off = 0;
  auto carve = [&](size_t bytes) -> void* {
    void* p = ws + off;
    off += (bytes + 255) & ~(size_t)255;
    return p;
  };
  unsigned long long* packed = (unsigned long long*)carve((size_t)N * 8);
  int*   fillc   = (int*)carve((size_t)N * 4);
  float* dinv    = (float*)carve((size_t)N * 4);
  int*   row_ptr = (int*)carve((size_t)(N + 1) * 4);
  int*   parts   = (int*)carve(256 * 4);
  int2*  epair   = (int2*)carve((size_t)E * 8);
  float* bufF    = (float*)carve((size_t)N * 128 * 4);                 // fp32 h
  unsigned short* bufH = (unsigned short*)carve((size_t)N * 128 * 2);  // fp16 xw
  (void)ws_size; (void)n_in; (void)out_size;

  const int nThreads = 256;
  int gN  = (N + nThreads - 1) / nThreads;
  int gE  = (E + nThreads - 1) / nThreads;
  int nb  = (N + 1023) / 1024;               // scan blocks (98)

  // --- graph preprocessing (shared across the 3 layers) ---
  hipMemsetAsync(packed, 0, (size_t)N * 8, stream);
  hipMemsetAsync(fillc, 0, (size_t)N * 4, stream);
  edge_pass_kernel<<<gE, nThreads, 0, stream>>>(ei, ew, packed, E);
  dinv_kernel<<<gN, nThreads, 0, stream>>>(packed, dinv, N);
  scanA<<<nb, 1024, 0, stream>>>(packed, row_ptr, parts, N);
  scanB<<<1, 128, 0, stream>>>(parts, nb);
  scanC<<<nb, 1024, 0, stream>>>(row_ptr, parts, N);
  fill_kernel<<<gE, nThreads, 0, stream>>>(ei, ew, dinv, row_ptr, fillc, epair, E);

  const int gMM = (N + 63) / 64;             // 1563 MFMA blocks (64 rows each)
  int gAgg128 = (N * 32 + nThreads - 1) / nThreads;
  int gAgg64  = (N * 16 + nThreads - 1) / nThreads;

  // --- layer 1: xw1 = fp16(x@W1) -> bufH; aggregate+bias+relu -> bufF ---
  gemm_mfma_kernel<128><<<gMM, 256, 0, stream>>>(x, W1, bufH, N);
  agg_kernel<128, true><<<gAgg128, nThreads, 0, stream>>>(bufH, row_ptr, epair, dinv, b1, bufF, N);

  // --- layer 2 (bufF -> bufH -> bufF) ---
  gemm_mfma_kernel<128><<<gMM, 256, 0, stream>>>(bufF, W2, bufH, N);
  agg_kernel<128, true><<<gAgg128, nThreads, 0, stream>>>(bufH, row_ptr, epair, dinv, b2, bufF, N);

  // --- layer 3 (64-wide, no relu) -> d_out ---
  gemm_mfma_kernel<64><<<gMM, 256, 0, stream>>>(bufF, W3, bufH, N);
  agg_kernel<64, false><<<gAgg64, nThreads, 0, stream>>>(bufH, row_ptr, epair, dinv, b3, (float*)d_out, N);
}

// Round 9
// 365.686 us; speedup vs baseline: 1.4679x; 1.1078x over previous
//
#include <hip/hip_runtime.h>
#include <hip/hip_fp16.h>
#include <math.h>

// ---------------------------------------------------------------------------
// GCN 3-layer forward on MI355X.
// Round 8 change: fill_kernel was atomic-bound (1.6M fillc atomics -> 102MB
// memory-side RMW traffic, 80us). edge_pass's packed atomicAdd already
// returns each edge's rank in its dst bucket (old>>32) -> store rank[e]
// (coalesced) in edge_pass; fill becomes atomic-free: p=row_ptr[d]+rank[e].
// ---------------------------------------------------------------------------

typedef __bf16 bf16x8 __attribute__((ext_vector_type(8)));
typedef float f32x4 __attribute__((ext_vector_type(4)));

union BF8 {
  unsigned short u[8];
  uint4 q;
  bf16x8 v;
};

__device__ __forceinline__ unsigned short rne_bf16(float f) {
  unsigned u = __float_as_uint(f);
  u += 0x7fff + ((u >> 16) & 1);
  return (unsigned short)(u >> 16);
}
__device__ __forceinline__ float bf16_to_f(unsigned short h) {
  return __uint_as_float((unsigned)h << 16);
}

__global__ __launch_bounds__(256) void edge_pass_kernel(const int* __restrict__ ei,
    const float* __restrict__ ew, unsigned long long* __restrict__ packed,
    int* __restrict__ rank, int E) {
  int e = blockIdx.x * 256 + threadIdx.x;
  if (e >= E) return;
  int d = ei[E + e];                       // dst row of edge_index
  unsigned wfix = (unsigned)__float2uint_rn(ew[e] * 16777216.0f);  // Q24
  unsigned long long inc = (1ULL << 32) | (unsigned long long)wfix;
  unsigned long long old = atomicAdd(&packed[d], inc);
  rank[e] = (int)(old >> 32);              // edge's slot within its dst bucket
}

__global__ __launch_bounds__(256) void dinv_kernel(const unsigned long long* __restrict__ packed,
    float* __restrict__ dinv, int n) {
  int i = blockIdx.x * 256 + threadIdx.x;
  if (i >= n) return;
  float deg = 1.0f + (float)(unsigned)(packed[i] & 0xffffffffULL) * (1.0f / 16777216.0f);
  dinv[i] = 1.0f / sqrtf(deg);             // deg >= 1 always (self-loop weight 1)
}

// ---- 3-kernel exclusive scan of counts (hi32 of packed) -> row_ptr ---------
__global__ __launch_bounds__(1024) void scanA(const unsigned long long* __restrict__ packed,
    int* __restrict__ row_ptr, int* __restrict__ partials, int n) {
  __shared__ int sd[1024];
  int t = threadIdx.x;
  int i = blockIdx.x * 1024 + t;
  int v = (i < n) ? (int)(packed[i] >> 32) : 0;
  sd[t] = v;
  __syncthreads();
  for (int off = 1; off < 1024; off <<= 1) {
    int u = (t >= off) ? sd[t - off] : 0;
    __syncthreads();
    sd[t] += u;
    __syncthreads();
  }
  int incl = sd[t];
  if (i < n) row_ptr[i] = incl - v;           // block-local exclusive
  if (t == 1023) partials[blockIdx.x] = incl; // block total
}

__global__ __launch_bounds__(128) void scanB(int* partials, int nb) {
  __shared__ int sd[128];
  int t = threadIdx.x;
  int v = (t < nb) ? partials[t] : 0;
  sd[t] = v;
  __syncthreads();
  for (int off = 1; off < 128; off <<= 1) {
    int u = (t >= off) ? sd[t - off] : 0;
    __syncthreads();
    sd[t] += u;
    __syncthreads();
  }
  int incl = sd[t];
  partials[t] = incl - v;                     // exclusive block offsets
  if (t == nb - 1) partials[255] = incl;      // grand total -> slot 255
}

__global__ __launch_bounds__(1024) void scanC(int* row_ptr, const int* __restrict__ partials, int n) {
  int i = blockIdx.x * 1024 + threadIdx.x;
  if (i < n) row_ptr[i] += partials[blockIdx.x];
  if (i == 0) row_ptr[n] = partials[255];
}

__global__ __launch_bounds__(256) void fill_kernel(const int* __restrict__ ei,
    const float* __restrict__ ew, const float* __restrict__ dinv,
    const int* __restrict__ row_ptr, const int* __restrict__ rank,
    int2* __restrict__ epair, int E) {
  int e = blockIdx.x * 256 + threadIdx.x;
  if (e >= E) return;
  int s = ei[e], d = ei[E + e];
  float nw = dinv[s] * ew[e] * dinv[d];
  int p = row_ptr[d] + rank[e];               // atomic-free slot
  epair[p] = make_int2(s, __float_as_int(nw));
}

// ---- MFMA split-bf16 GEMM: Ch[M,NCOL] = fp16(A[M,128] @ W[128,NCOL]) -------
// Block: 256 thr = 4 waves, 64 rows (16/wave) x NCOL cols. K=128 in 4 steps.
// LDS: WT[2][NCOL][128] bf16 (hi,lo), transposed W, k-index XOR-swizzled by
// (n&7)<<3 -> B-frag ds_read_b128 ~conflict-free. A from global, 1-step
// prefetch. Fragments (16x16x32): A/B lane l -> row/col=l&15, k=(l>>4)*8+j;
// C/D lane l reg j -> col=l&15, row=(l>>4)*4+j (HW-verified mapping).
template <int NCOL>
__global__ __launch_bounds__(256) void gemm_mfma_kernel(const float* __restrict__ A,
    const float* __restrict__ W, unsigned short* __restrict__ Ch, int M) {
  constexpr int NF = NCOL / 16;
  __shared__ __align__(16) unsigned short WT[2][NCOL][128];
  const int t = threadIdx.x;
  constexpr int KC_PER_IT = 256 / NCOL;       // k-chunks advanced per iter
#pragma unroll
  for (int it = 0; it < 16 / KC_PER_IT; ++it) {
    int n = t % NCOL;
    int kc = it * KC_PER_IT + t / NCOL;
    int k0 = kc * 8;
    BF8 hh, ll;
#pragma unroll
    for (int j = 0; j < 8; ++j) {
      float w = W[(size_t)(k0 + j) * NCOL + n];
      unsigned short hb = rne_bf16(w);
      hh.u[j] = hb;
      ll.u[j] = rne_bf16(w - bf16_to_f(hb));
    }
    int kk = k0 ^ ((n & 7) << 3);
    *(uint4*)&WT[0][n][kk] = hh.q;
    *(uint4*)&WT[1][n][kk] = ll.q;
  }
  __syncthreads();

  const int wv = t >> 6;                      // wave 0..3
  const int l = t & 63;
  const int lr = l & 15;                      // A-row / B-col / C-col selector
  const int lg = l >> 4;                      // k-group
  const int arow_i = blockIdx.x * 64 + wv * 16 + lr;
  const bool rv = arow_i < M;
  const float* arow = A + (size_t)arow_i * 128;

  f32x4 acc[NF] = {};
  float4 p0 = make_float4(0.f, 0.f, 0.f, 0.f), p1 = p0;
  if (rv) {
    p0 = *(const float4*)&arow[lg * 8];
    p1 = *(const float4*)&arow[lg * 8 + 4];
  }
#pragma unroll 1
  for (int ks = 0; ks < 4; ++ks) {
    int nkb = ((ks < 3) ? (ks + 1) * 32 : ks * 32) + lg * 8;
    float4 q0 = make_float4(0.f, 0.f, 0.f, 0.f), q1 = q0;
    if (rv) {
      q0 = *(const float4*)&arow[nkb];
      q1 = *(const float4*)&arow[nkb + 4];
    }
    float av[8] = {p0.x, p0.y, p0.z, p0.w, p1.x, p1.y, p1.z, p1.w};
    BF8 ah, al;
#pragma unroll
    for (int j = 0; j < 8; ++j) {
      unsigned short hb = rne_bf16(av[j]);
      ah.u[j] = hb;
      al.u[j] = rne_bf16(av[j] - bf16_to_f(hb));
    }
    int kidx = ks * 32 + lg * 8;
    BF8 bh[NF], bl[NF];
#pragma unroll
    for (int nf = 0; nf < NF; ++nf) {
      int n = nf * 16 + lr;
      int kk = kidx ^ ((n & 7) << 3);
      bh[nf].q = *(const uint4*)&WT[0][n][kk];
      bl[nf].q = *(const uint4*)&WT[1][n][kk];
    }
#pragma unroll
    for (int nf = 0; nf < NF; ++nf) {
      acc[nf] = __builtin_amdgcn_mfma_f32_16x16x32_bf16(ah.v, bh[nf].v, acc[nf], 0, 0, 0);
      acc[nf] = __builtin_amdgcn_mfma_f32_16x16x32_bf16(al.v, bh[nf].v, acc[nf], 0, 0, 0);
      acc[nf] = __builtin_amdgcn_mfma_f32_16x16x32_bf16(ah.v, bl[nf].v, acc[nf], 0, 0, 0);
    }
    p0 = q0; p1 = q1;
  }
  const int orow0 = blockIdx.x * 64 + wv * 16 + lg * 4;
#pragma unroll
  for (int j = 0; j < 4; ++j) {
    int orow = orow0 + j;
    if (orow < M) {
      unsigned short* hr = Ch + (size_t)orow * NCOL;
#pragma unroll
      for (int nf = 0; nf < NF; ++nf)
        hr[nf * 16 + lr] = __half_as_ushort(__float2half(acc[nf][j]));
    }
  }
}

// ---- aggregation: out[n] = sum_{e: dst=n} norm_e * xw[src_e] + dinv^2*xw[n] + b
// All xw reads fp16 (gather 8B/lane, x4 unrolled; self-row also fp16).
template <int F, bool RELU>
__global__ __launch_bounds__(256) void agg_kernel(const unsigned short* __restrict__ xwh,
    const int* __restrict__ row_ptr, const int2* __restrict__ epair,
    const float* __restrict__ dinv, const float* __restrict__ bias,
    float* __restrict__ out, int Nn) {
  constexpr int LPN = F / 4;                  // lanes per node (4 dims each)
  int t = blockIdx.x * 256 + threadIdx.x;
  int node = t / LPN;
  int lane = t % LPN;
  if (node >= Nn) return;
  const uint2* xh = (const uint2*)xwh;        // 4 halves per uint2
  int start = row_ptr[node];
  int end = row_ptr[node + 1];
  float a0x = 0.f, a0y = 0.f, a0z = 0.f, a0w = 0.f;   // chain 0
  float a1x = 0.f, a1y = 0.f, a1z = 0.f, a1w = 0.f;   // chain 1
  int p = start;
  for (; p + 4 <= end; p += 4) {
    int2 e0 = epair[p];
    int2 e1 = epair[p + 1];
    int2 e2 = epair[p + 2];
    int2 e3 = epair[p + 3];
    uint2 u0 = xh[(size_t)e0.x * LPN + lane];
    uint2 u1 = xh[(size_t)e1.x * LPN + lane];
    uint2 u2 = xh[(size_t)e2.x * LPN + lane];
    uint2 u3 = xh[(size_t)e3.x * LPN + lane];
    float n0 = __int_as_float(e0.y), n1 = __int_as_float(e1.y);
    float n2 = __int_as_float(e2.y), n3 = __int_as_float(e3.y);
    float2 f0a = __half22float2(*(__half2*)&u0.x), f0b = __half22float2(*(__half2*)&u0.y);
    float2 f1a = __half22float2(*(__half2*)&u1.x), f1b = __half22float2(*(__half2*)&u1.y);
    float2 f2a = __half22float2(*(__half2*)&u2.x), f2b = __half22float2(*(__half2*)&u2.y);
    float2 f3a = __half22float2(*(__half2*)&u3.x), f3b = __half22float2(*(__half2*)&u3.y);
    a0x = fmaf(n0, f0a.x, a0x); a0y = fmaf(n0, f0a.y, a0y);
    a0z = fmaf(n0, f0b.x, a0z); a0w = fmaf(n0, f0b.y, a0w);
    a1x = fmaf(n1, f1a.x, a1x); a1y = fmaf(n1, f1a.y, a1y);
    a1z = fmaf(n1, f1b.x, a1z); a1w = fmaf(n1, f1b.y, a1w);
    a0x = fmaf(n2, f2a.x, a0x); a0y = fmaf(n2, f2a.y, a0y);
    a0z = fmaf(n2, f2b.x, a0z); a0w = fmaf(n2, f2b.y, a0w);
    a1x = fmaf(n3, f3a.x, a1x); a1y = fmaf(n3, f3a.y, a1y);
    a1z = fmaf(n3, f3b.x, a1z); a1w = fmaf(n3, f3b.y, a1w);
  }
  for (; p < end; ++p) {
    int2 pr = epair[p];
    float nw = __int_as_float(pr.y);
    uint2 u = xh[(size_t)pr.x * LPN + lane];
    float2 fa = __half22float2(*(__half2*)&u.x), fb = __half22float2(*(__half2*)&u.y);
    a0x = fmaf(nw, fa.x, a0x); a0y = fmaf(nw, fa.y, a0y);
    a0z = fmaf(nw, fb.x, a0z); a0w = fmaf(nw, fb.y, a0w);
  }
  float di = dinv[node];
  float sw = di * di;
  uint2 su = xh[(size_t)node * LPN + lane];   // fp16 self row
  float2 sa = __half22float2(*(__half2*)&su.x), sb = __half22float2(*(__half2*)&su.y);
  a0x = fmaf(sw, sa.x, a0x); a0y = fmaf(sw, sa.y, a0y);
  a0z = fmaf(sw, sb.x, a0z); a0w = fmaf(sw, sb.y, a0w);
  float4 b = ((const float4*)bias)[lane];
  float ox = a0x + a1x + b.x;
  float oy = a0y + a1y + b.y;
  float oz = a0z + a1z + b.z;
  float ow = a0w + a1w + b.w;
  if (RELU) {
    ox = fmaxf(ox, 0.f); oy = fmaxf(oy, 0.f);
    oz = fmaxf(oz, 0.f); ow = fmaxf(ow, 0.f);
  }
  ((float4*)out)[(size_t)node * LPN + lane] = make_float4(ox, oy, oz, ow);
}

// ---------------------------------------------------------------------------
extern "C" void kernel_launch(void* const* d_in, const int* in_sizes, int n_in,
                              void* d_out, int out_size, void* d_ws, size_t ws_size,
                              hipStream_t stream) {
  const float* x  = (const float*)d_in[0];
  const int*   ei = (const int*)d_in[1];     // int32, [2,E] flat
  const float* ew = (const float*)d_in[2];
  const float* W1 = (const float*)d_in[3];
  const float* b1 = (const float*)d_in[4];
  const float* W2 = (const float*)d_in[5];
  const float* b2 = (const float*)d_in[6];
  const float* W3 = (const float*)d_in[7];
  const float* b3 = (const float*)d_in[8];

  const int N = in_sizes[0] / 128;           // 100000
  const int E = in_sizes[2];                 // 1600000

  // workspace carve (256B aligned)
  char* ws = (char*)d_ws;
  size_t off = 0;
  auto carve = [&](size_t bytes) -> void* {
    void* p = ws + off;
    off += (bytes + 255) & ~(size_t)255;
    return p;
  };
  unsigned long long* packed = (unsigned long long*)carve((size_t)N * 8);
  int*   rank    = (int*)carve((size_t)E * 4);
  float* dinv    = (float*)carve((size_t)N * 4);
  int*   row_ptr = (int*)carve((size_t)(N + 1) * 4);
  int*   parts   = (int*)carve(256 * 4);
  int2*  epair   = (int2*)carve((size_t)E * 8);
  float* bufF    = (float*)carve((size_t)N * 128 * 4);                 // fp32 h
  unsigned short* bufH = (unsigned short*)carve((size_t)N * 128 * 2);  // fp16 xw
  (void)ws_size; (void)n_in; (void)out_size;

  const int nThreads = 256;
  int gN  = (N + nThreads - 1) / nThreads;
  int gE  = (E + nThreads - 1) / nThreads;
  int nb  = (N + 1023) / 1024;               // scan blocks (98)

  // --- graph preprocessing (shared across the 3 layers) ---
  hipMemsetAsync(packed, 0, (size_t)N * 8, stream);
  edge_pass_kernel<<<gE, nThreads, 0, stream>>>(ei, ew, packed, rank, E);
  dinv_kernel<<<gN, nThreads, 0, stream>>>(packed, dinv, N);
  scanA<<<nb, 1024, 0, stream>>>(packed, row_ptr, parts, N);
  scanB<<<1, 128, 0, stream>>>(parts, nb);
  scanC<<<nb, 1024, 0, stream>>>(row_ptr, parts, N);
  fill_kernel<<<gE, nThreads, 0, stream>>>(ei, ew, dinv, row_ptr, rank, epair, E);

  const int gMM = (N + 63) / 64;             // 1563 MFMA blocks (64 rows each)
  int gAgg128 = (N * 32 + nThreads - 1) / nThreads;
  int gAgg64  = (N * 16 + nThreads - 1) / nThreads;

  // --- layer 1: xw1 = fp16(x@W1) -> bufH; aggregate+bias+relu -> bufF ---
  gemm_mfma_kernel<128><<<gMM, 256, 0, stream>>>(x, W1, bufH, N);
  agg_kernel<128, true><<<gAgg128, nThreads, 0, stream>>>(bufH, row_ptr, epair, dinv, b1, bufF, N);

  // --- layer 2 (bufF -> bufH -> bufF) ---
  gemm_mfma_kernel<128><<<gMM, 256, 0, stream>>>(bufF, W2, bufH, N);
  agg_kernel<128, true><<<gAgg128, nThreads, 0, stream>>>(bufH, row_ptr, epair, dinv, b2, bufF, N);

  // --- layer 3 (64-wide, no relu) -> d_out ---
  gemm_mfma_kernel<64><<<gMM, 256, 0, stream>>>(bufF, W3, bufH, N);
  agg_kernel<64, false><<<gAgg64, nThreads, 0, stream>>>(bufH, row_ptr, epair, dinv, b3, (float*)d_out, N);
}

// Round 10
// 347.935 us; speedup vs baseline: 1.5428x; 1.0510x over previous
//
#include <hip/hip_runtime.h>
#include <hip/hip_fp16.h>
#include <math.h>

// ---------------------------------------------------------------------------
// GCN 3-layer forward on MI355X.
// Round 9 changes:
//  - edge_pass (75us, atomic-op bound, CUs idle) co-dispatched with layer-1
//    MFMA GEMM in ONE block-partitioned kernel: gemm blocks fill the compute
//    shadow of the atomic grind.
//  - h1/h2 stored fp16 (exact bf16 hi/lo split feeds gemm2/3): agg writes and
//    gemm A-reads halved. Layer-3 output stays fp32.
// ---------------------------------------------------------------------------

typedef __bf16 bf16x8 __attribute__((ext_vector_type(8)));
typedef float f32x4 __attribute__((ext_vector_type(4)));

union BF8 {
  unsigned short u[8];
  uint4 q;
  bf16x8 v;
};

__device__ __forceinline__ unsigned short rne_bf16(float f) {
  unsigned u = __float_as_uint(f);
  u += 0x7fff + ((u >> 16) & 1);
  return (unsigned short)(u >> 16);
}
__device__ __forceinline__ float bf16_to_f(unsigned short h) {
  return __uint_as_float((unsigned)h << 16);
}

// ---- MFMA split-bf16 GEMM body: Ch[M,NCOL] = fp16(A[M,128] @ W[128,NCOL]) --
// 256 thr = 4 waves, 64 rows x NCOL cols, K=128 in 4 steps. W in LDS as bf16
// hi/lo transposed + XOR-swizzled; A from global (fp32 or fp16), 1-step
// prefetch. 3-term: AhWh + AlWh + AhWl.
template <int NCOL, bool AH>
__device__ __forceinline__ void gemm_body(const void* Av, const float* __restrict__ W,
    unsigned short* __restrict__ Ch, int M, int bid) {
  constexpr int NF = NCOL / 16;
  __shared__ __align__(16) unsigned short WT[2][NCOL][128];
  const int t = threadIdx.x;
  constexpr int KC_PER_IT = 256 / NCOL;
#pragma unroll
  for (int it = 0; it < 16 / KC_PER_IT; ++it) {
    int n = t % NCOL;
    int kc = it * KC_PER_IT + t / NCOL;
    int k0 = kc * 8;
    BF8 hh, ll;
#pragma unroll
    for (int j = 0; j < 8; ++j) {
      float w = W[(size_t)(k0 + j) * NCOL + n];
      unsigned short hb = rne_bf16(w);
      hh.u[j] = hb;
      ll.u[j] = rne_bf16(w - bf16_to_f(hb));
    }
    int kk = k0 ^ ((n & 7) << 3);
    *(uint4*)&WT[0][n][kk] = hh.q;
    *(uint4*)&WT[1][n][kk] = ll.q;
  }
  __syncthreads();

  const int wv = t >> 6;
  const int l = t & 63;
  const int lr = l & 15;
  const int lg = l >> 4;
  const int arow_i = bid * 64 + wv * 16 + lr;
  const bool rv = arow_i < M;

  const float* arowf = (const float*)Av + (size_t)arow_i * 128;
  const unsigned short* arowh = (const unsigned short*)Av + (size_t)arow_i * 128;

  f32x4 acc[NF] = {};
  float4 p0 = make_float4(0.f, 0.f, 0.f, 0.f), p1 = p0;
  uint4 ph = make_uint4(0, 0, 0, 0);
  if (rv) {
    if constexpr (AH) {
      ph = *(const uint4*)&arowh[lg * 8];
    } else {
      p0 = *(const float4*)&arowf[lg * 8];
      p1 = *(const float4*)&arowf[lg * 8 + 4];
    }
  }
#pragma unroll 1
  for (int ks = 0; ks < 4; ++ks) {
    int nkb = ((ks < 3) ? (ks + 1) * 32 : ks * 32) + lg * 8;
    float4 q0 = make_float4(0.f, 0.f, 0.f, 0.f), q1 = q0;
    uint4 qh = make_uint4(0, 0, 0, 0);
    if (rv) {
      if constexpr (AH) {
        qh = *(const uint4*)&arowh[nkb];
      } else {
        q0 = *(const float4*)&arowf[nkb];
        q1 = *(const float4*)&arowf[nkb + 4];
      }
    }
    float av[8];
    if constexpr (AH) {
      union { uint4 q; __half2 h2[4]; } uu;
      uu.q = ph;
#pragma unroll
      for (int j = 0; j < 4; ++j) {
        float2 f = __half22float2(uu.h2[j]);
        av[j * 2] = f.x; av[j * 2 + 1] = f.y;
      }
    } else {
      av[0] = p0.x; av[1] = p0.y; av[2] = p0.z; av[3] = p0.w;
      av[4] = p1.x; av[5] = p1.y; av[6] = p1.z; av[7] = p1.w;
    }
    BF8 ah, al;
#pragma unroll
    for (int j = 0; j < 8; ++j) {
      unsigned short hb = rne_bf16(av[j]);
      ah.u[j] = hb;
      al.u[j] = rne_bf16(av[j] - bf16_to_f(hb));
    }
    int kidx = ks * 32 + lg * 8;
    BF8 bh[NF], bl[NF];
#pragma unroll
    for (int nf = 0; nf < NF; ++nf) {
      int n = nf * 16 + lr;
      int kk = kidx ^ ((n & 7) << 3);
      bh[nf].q = *(const uint4*)&WT[0][n][kk];
      bl[nf].q = *(const uint4*)&WT[1][n][kk];
    }
#pragma unroll
    for (int nf = 0; nf < NF; ++nf) {
      acc[nf] = __builtin_amdgcn_mfma_f32_16x16x32_bf16(ah.v, bh[nf].v, acc[nf], 0, 0, 0);
      acc[nf] = __builtin_amdgcn_mfma_f32_16x16x32_bf16(al.v, bh[nf].v, acc[nf], 0, 0, 0);
      acc[nf] = __builtin_amdgcn_mfma_f32_16x16x32_bf16(ah.v, bl[nf].v, acc[nf], 0, 0, 0);
    }
    p0 = q0; p1 = q1; ph = qh;
  }
  const int orow0 = bid * 64 + wv * 16 + lg * 4;
#pragma unroll
  for (int j = 0; j < 4; ++j) {
    int orow = orow0 + j;
    if (orow < M) {
      unsigned short* hr = Ch + (size_t)orow * NCOL;
#pragma unroll
      for (int nf = 0; nf < NF; ++nf)
        hr[nf * 16 + lr] = __half_as_ushort(__float2half(acc[nf][j]));
    }
  }
}

// fused dispatch: blocks [0,gemmBlocks) = layer-1 GEMM; rest = edge_pass.
__global__ __launch_bounds__(256) void pre_gemm_fused_kernel(
    const float* __restrict__ x, const float* __restrict__ W1,
    unsigned short* __restrict__ Ch, int M,
    const int* __restrict__ ei, const float* __restrict__ ew,
    unsigned long long* __restrict__ packed, int* __restrict__ rank,
    int E, int gemmBlocks) {
  if ((int)blockIdx.x < gemmBlocks) {
    gemm_body<128, false>(x, W1, Ch, M, blockIdx.x);
  } else {
    int e = (blockIdx.x - gemmBlocks) * 256 + threadIdx.x;
    if (e >= E) return;
    int d = ei[E + e];
    unsigned wfix = (unsigned)__float2uint_rn(ew[e] * 16777216.0f);  // Q24
    unsigned long long inc = (1ULL << 32) | (unsigned long long)wfix;
    unsigned long long old = atomicAdd(&packed[d], inc);
    rank[e] = (int)(old >> 32);
  }
}

template <int NCOL, bool AH>
__global__ __launch_bounds__(256) void gemm_mfma_kernel(const void* __restrict__ A,
    const float* __restrict__ W, unsigned short* __restrict__ Ch, int M) {
  gemm_body<NCOL, AH>(A, W, Ch, M, blockIdx.x);
}

__global__ __launch_bounds__(256) void dinv_kernel(const unsigned long long* __restrict__ packed,
    float* __restrict__ dinv, int n) {
  int i = blockIdx.x * 256 + threadIdx.x;
  if (i >= n) return;
  float deg = 1.0f + (float)(unsigned)(packed[i] & 0xffffffffULL) * (1.0f / 16777216.0f);
  dinv[i] = 1.0f / sqrtf(deg);
}

// ---- 3-kernel exclusive scan of counts (hi32 of packed) -> row_ptr ---------
__global__ __launch_bounds__(1024) void scanA(const unsigned long long* __restrict__ packed,
    int* __restrict__ row_ptr, int* __restrict__ partials, int n) {
  __shared__ int sd[1024];
  int t = threadIdx.x;
  int i = blockIdx.x * 1024 + t;
  int v = (i < n) ? (int)(packed[i] >> 32) : 0;
  sd[t] = v;
  __syncthreads();
  for (int off = 1; off < 1024; off <<= 1) {
    int u = (t >= off) ? sd[t - off] : 0;
    __syncthreads();
    sd[t] += u;
    __syncthreads();
  }
  int incl = sd[t];
  if (i < n) row_ptr[i] = incl - v;
  if (t == 1023) partials[blockIdx.x] = incl;
}

__global__ __launch_bounds__(128) void scanB(int* partials, int nb) {
  __shared__ int sd[128];
  int t = threadIdx.x;
  int v = (t < nb) ? partials[t] : 0;
  sd[t] = v;
  __syncthreads();
  for (int off = 1; off < 128; off <<= 1) {
    int u = (t >= off) ? sd[t - off] : 0;
    __syncthreads();
    sd[t] += u;
    __syncthreads();
  }
  int incl = sd[t];
  partials[t] = incl - v;
  if (t == nb - 1) partials[255] = incl;
}

__global__ __launch_bounds__(1024) void scanC(int* row_ptr, const int* __restrict__ partials, int n) {
  int i = blockIdx.x * 1024 + threadIdx.x;
  if (i < n) row_ptr[i] += partials[blockIdx.x];
  if (i == 0) row_ptr[n] = partials[255];
}

__global__ __launch_bounds__(256) void fill_kernel(const int* __restrict__ ei,
    const float* __restrict__ ew, const float* __restrict__ dinv,
    const int* __restrict__ row_ptr, const int* __restrict__ rank,
    int2* __restrict__ epair, int E) {
  int e = blockIdx.x * 256 + threadIdx.x;
  if (e >= E) return;
  int s = ei[e], d = ei[E + e];
  float nw = dinv[s] * ew[e] * dinv[d];
  int p = row_ptr[d] + rank[e];
  epair[p] = make_int2(s, __float_as_int(nw));
}

// ---- aggregation: out[n] = sum_{e: dst=n} norm_e * xw[src_e] + dinv^2*xw[n] + b
// Gather fp16 (8B/lane, x4 unrolled); output fp16 (h1,h2) or fp32 (layer 3).
template <int F, bool RELU, bool OUTF16>
__global__ __launch_bounds__(256) void agg_kernel(const unsigned short* __restrict__ xwh,
    const int* __restrict__ row_ptr, const int2* __restrict__ epair,
    const float* __restrict__ dinv, const float* __restrict__ bias,
    void* __restrict__ out, int Nn) {
  constexpr int LPN = F / 4;
  int t = blockIdx.x * 256 + threadIdx.x;
  int node = t / LPN;
  int lane = t % LPN;
  if (node >= Nn) return;
  const uint2* xh = (const uint2*)xwh;
  int start = row_ptr[node];
  int end = row_ptr[node + 1];
  float a0x = 0.f, a0y = 0.f, a0z = 0.f, a0w = 0.f;
  float a1x = 0.f, a1y = 0.f, a1z = 0.f, a1w = 0.f;
  int p = start;
  for (; p + 4 <= end; p += 4) {
    int2 e0 = epair[p];
    int2 e1 = epair[p + 1];
    int2 e2 = epair[p + 2];
    int2 e3 = epair[p + 3];
    uint2 u0 = xh[(size_t)e0.x * LPN + lane];
    uint2 u1 = xh[(size_t)e1.x * LPN + lane];
    uint2 u2 = xh[(size_t)e2.x * LPN + lane];
    uint2 u3 = xh[(size_t)e3.x * LPN + lane];
    float n0 = __int_as_float(e0.y), n1 = __int_as_float(e1.y);
    float n2 = __int_as_float(e2.y), n3 = __int_as_float(e3.y);
    float2 f0a = __half22float2(*(__half2*)&u0.x), f0b = __half22float2(*(__half2*)&u0.y);
    float2 f1a = __half22float2(*(__half2*)&u1.x), f1b = __half22float2(*(__half2*)&u1.y);
    float2 f2a = __half22float2(*(__half2*)&u2.x), f2b = __half22float2(*(__half2*)&u2.y);
    float2 f3a = __half22float2(*(__half2*)&u3.x), f3b = __half22float2(*(__half2*)&u3.y);
    a0x = fmaf(n0, f0a.x, a0x); a0y = fmaf(n0, f0a.y, a0y);
    a0z = fmaf(n0, f0b.x, a0z); a0w = fmaf(n0, f0b.y, a0w);
    a1x = fmaf(n1, f1a.x, a1x); a1y = fmaf(n1, f1a.y, a1y);
    a1z = fmaf(n1, f1b.x, a1z); a1w = fmaf(n1, f1b.y, a1w);
    a0x = fmaf(n2, f2a.x, a0x); a0y = fmaf(n2, f2a.y, a0y);
    a0z = fmaf(n2, f2b.x, a0z); a0w = fmaf(n2, f2b.y, a0w);
    a1x = fmaf(n3, f3a.x, a1x); a1y = fmaf(n3, f3a.y, a1y);
    a1z = fmaf(n3, f3b.x, a1z); a1w = fmaf(n3, f3b.y, a1w);
  }
  for (; p < end; ++p) {
    int2 pr = epair[p];
    float nw = __int_as_float(pr.y);
    uint2 u = xh[(size_t)pr.x * LPN + lane];
    float2 fa = __half22float2(*(__half2*)&u.x), fb = __half22float2(*(__half2*)&u.y);
    a0x = fmaf(nw, fa.x, a0x); a0y = fmaf(nw, fa.y, a0y);
    a0z = fmaf(nw, fb.x, a0z); a0w = fmaf(nw, fb.y, a0w);
  }
  float di = dinv[node];
  float sw = di * di;
  uint2 su = xh[(size_t)node * LPN + lane];
  float2 sa = __half22float2(*(__half2*)&su.x), sb = __half22float2(*(__half2*)&su.y);
  a0x = fmaf(sw, sa.x, a0x); a0y = fmaf(sw, sa.y, a0y);
  a0z = fmaf(sw, sb.x, a0z); a0w = fmaf(sw, sb.y, a0w);
  float4 b = ((const float4*)bias)[lane];
  float ox = a0x + a1x + b.x;
  float oy = a0y + a1y + b.y;
  float oz = a0z + a1z + b.z;
  float ow = a0w + a1w + b.w;
  if (RELU) {
    ox = fmaxf(ox, 0.f); oy = fmaxf(oy, 0.f);
    oz = fmaxf(oz, 0.f); ow = fmaxf(ow, 0.f);
  }
  if constexpr (OUTF16) {
    uint2 o;
    __half2 h0 = __float22half2_rn(make_float2(ox, oy));
    __half2 h1 = __float22half2_rn(make_float2(oz, ow));
    o.x = *reinterpret_cast<unsigned*>(&h0);
    o.y = *reinterpret_cast<unsigned*>(&h1);
    ((uint2*)out)[(size_t)node * LPN + lane] = o;
  } else {
    ((float4*)out)[(size_t)node * LPN + lane] = make_float4(ox, oy, oz, ow);
  }
}

// ---------------------------------------------------------------------------
extern "C" void kernel_launch(void* const* d_in, const int* in_sizes, int n_in,
                              void* d_out, int out_size, void* d_ws, size_t ws_size,
                              hipStream_t stream) {
  const float* x  = (const float*)d_in[0];
  const int*   ei = (const int*)d_in[1];     // int32, [2,E] flat
  const float* ew = (const float*)d_in[2];
  const float* W1 = (const float*)d_in[3];
  const float* b1 = (const float*)d_in[4];
  const float* W2 = (const float*)d_in[5];
  const float* b2 = (const float*)d_in[6];
  const float* W3 = (const float*)d_in[7];
  const float* b3 = (const float*)d_in[8];

  const int N = in_sizes[0] / 128;           // 100000
  const int E = in_sizes[2];                 // 1600000

  // workspace carve (256B aligned)
  char* ws = (char*)d_ws;
  size_t off = 0;
  auto carve = [&](size_t bytes) -> void* {
    void* p = ws + off;
    off += (bytes + 255) & ~(size_t)255;
    return p;
  };
  unsigned long long* packed = (unsigned long long*)carve((size_t)N * 8);
  int*   rank    = (int*)carve((size_t)E * 4);
  float* dinv    = (float*)carve((size_t)N * 4);
  int*   row_ptr = (int*)carve((size_t)(N + 1) * 4);
  int*   parts   = (int*)carve(256 * 4);
  int2*  epair   = (int2*)carve((size_t)E * 8);
  unsigned short* bufH = (unsigned short*)carve((size_t)N * 128 * 2);  // fp16 xw
  unsigned short* bufI = (unsigned short*)carve((size_t)N * 128 * 2);  // fp16 h
  (void)ws_size; (void)n_in; (void)out_size;

  const int nThreads = 256;
  int gN  = (N + nThreads - 1) / nThreads;
  int gE  = (E + nThreads - 1) / nThreads;
  int nb  = (N + 1023) / 1024;               // scan blocks (98)
  const int gMM = (N + 63) / 64;             // 1563 MFMA blocks (64 rows each)
  int gAgg128 = (N * 32 + nThreads - 1) / nThreads;
  int gAgg64  = (N * 16 + nThreads - 1) / nThreads;

  // --- D1: layer-1 GEMM co-dispatched with edge_pass (independent work) ---
  hipMemsetAsync(packed, 0, (size_t)N * 8, stream);
  pre_gemm_fused_kernel<<<gMM + gE, nThreads, 0, stream>>>(
      x, W1, bufH, N, ei, ew, packed, rank, E, gMM);

  // --- graph preprocessing tail ---
  dinv_kernel<<<gN, nThreads, 0, stream>>>(packed, dinv, N);
  scanA<<<nb, 1024, 0, stream>>>(packed, row_ptr, parts, N);
  scanB<<<1, 128, 0, stream>>>(parts, nb);
  scanC<<<nb, 1024, 0, stream>>>(row_ptr, parts, N);
  fill_kernel<<<gE, nThreads, 0, stream>>>(ei, ew, dinv, row_ptr, rank, epair, E);

  // --- layer 1 aggregate -> fp16 h1 ---
  agg_kernel<128, true, true><<<gAgg128, nThreads, 0, stream>>>(bufH, row_ptr, epair, dinv, b1, bufI, N);

  // --- layer 2: gemm (fp16 A) -> bufH; agg -> fp16 h2 (reuse bufI) ---
  gemm_mfma_kernel<128, true><<<gMM, nThreads, 0, stream>>>(bufI, W2, bufH, N);
  agg_kernel<128, true, true><<<gAgg128, nThreads, 0, stream>>>(bufH, row_ptr, epair, dinv, b2, bufI, N);

  // --- layer 3: gemm 64-wide (fp16 A) -> bufH; agg -> fp32 d_out ---
  gemm_mfma_kernel<64, true><<<gMM, nThreads, 0, stream>>>(bufI, W3, bufH, N);
  agg_kernel<64, false, false><<<gAgg64, nThreads, 0, stream>>>(bufH, row_ptr, epair, dinv, b3, d_out, N);
}